// Round 3
// baseline (193.491 us; speedup 1.0000x reference)
//
#include <hip/hip_runtime.h>
#include <hip/hip_cooperative_groups.h>

namespace cg = cooperative_groups;

#define NPATH 16384
#define DIM   8
#define NINC  (NPATH - 1)        // 16383 increments / output rows
#define SIG   4680               // 8 + 64 + 512 + 4096
#define L1OFF 0
#define L2OFF 8
#define L3OFF 72
#define L4OFF 584
#define NBLK  256                // blocks (chunks), 1 per CU
#define CHUNK 64                 // increments per chunk
#define GSIZE 16                 // chunks per group
#define C6    0.16666666666666666f
#define LPAD  17                 // floats per thread in transpose buffer (16 + 1 pad)

// Per-thread register state (t = threadIdx.x, 256 threads):
//   r4[16] : level-4 rows c0=2t, c1=2t+1 of [512][8]
//   r3[2]  : level-3 elements 2t, 2t+1
//   a1i=a1[t>>5], a2v=a2[t>>2] (consumed by level-3/4 updates)
//   a2s=a2[t] (t<64), a1s=a1[t>>3] (t<64), a1t=a1[t] (t<8) (store mapping)

__device__ __forceinline__ void light_barrier() {
  // barrier that waits LDS ops only (not in-flight global output stores)
  asm volatile("s_waitcnt lgkmcnt(0)" ::: "memory");
  __builtin_amdgcn_s_barrier();
}

__device__ __forceinline__ void zero_state(float r4[16], float r3[2],
                                           float& a1i, float& a2v,
                                           float& a2s, float& a1s, float& a1t) {
#pragma unroll
  for (int l = 0; l < 16; ++l) r4[l] = 0.f;
  r3[0] = r3[1] = 0.f;
  a1i = a2v = a2s = a1s = a1t = 0.f;
}

// ---- store full signature from registers (global or LDS dst) ----
__device__ __forceinline__ void store_sig_reg(float* dst,
                                              const float r4[16], const float r3[2],
                                              float a2s, float a1t, int t) {
  float4* d4 = (float4*)(dst + L4OFF + 16 * t);
  d4[0] = make_float4(r4[0], r4[1], r4[2], r4[3]);
  d4[1] = make_float4(r4[4], r4[5], r4[6], r4[7]);
  d4[2] = make_float4(r4[8], r4[9], r4[10], r4[11]);
  d4[3] = make_float4(r4[12], r4[13], r4[14], r4[15]);
  *(float2*)(dst + L3OFF + 2 * t) = make_float2(r3[0], r3[1]);
  if (t < 64) dst[L2OFF + t] = a2s;
  if (t < 8)  dst[L1OFF + t] = a1t;
}

// ---- general Chen product a = a o b; b readable from global or LDS ----
__device__ __forceinline__ void chen_reg(float r4[16], float r3[2],
                                         float& a1i, float& a2v,
                                         float& a2s, float& a1s, float& a1t,
                                         const float* b, int t) {
  const int i   = t >> 5;
  const int j   = (t >> 2) & 7;
  const int ij  = t >> 2;
  const int c0  = 2 * t;
  const int jk0 = c0 & 63;          // even
  const int k0  = 2 * (t & 3);      // even
  const int i2  = t >> 3;
  const int j2  = t & 7;
  const float4* bv = (const float4*)b;
  float4 B0 = bv[146 + 4 * t], B1 = bv[147 + 4 * t], B2 = bv[148 + 4 * t], B3 = bv[149 + 4 * t];
  float4 Cq0 = bv[18 + 2 * jk0], Cq1 = bv[19 + 2 * jk0], Cq2 = bv[20 + 2 * jk0], Cq3 = bv[21 + 2 * jk0];
  float4 D0 = bv[2 + 2 * k0], D1 = bv[3 + 2 * k0], D2 = bv[4 + 2 * k0], D3 = bv[5 + 2 * k0];
  float4 E0 = bv[0], E1 = bv[1];
  const float2 b3c  = *(const float2*)(b + L3OFF + c0);
  const float2 b2jk = *(const float2*)(b + L2OFF + jk0);
  const float2 b1k  = *(const float2*)(b + L1OFF + k0);
  const float b2ij = b[L2OFF + ij];
  const float b1j  = b[L1OFF + j];
  const float b1i  = b[L1OFF + i];
  float b2t = 0.f, b1j2 = 0.f, b1i2 = 0.f, b1t = 0.f;
  if (t < 64) { b2t = b[L2OFF + t]; b1j2 = b[L1OFF + j2]; b1i2 = b[L1OFF + i2]; }
  if (t < 8)  { b1t = b[L1OFF + t]; }

  const float b4r[16] = {B0.x,B0.y,B0.z,B0.w, B1.x,B1.y,B1.z,B1.w,
                         B2.x,B2.y,B2.z,B2.w, B3.x,B3.y,B3.z,B3.w};
  const float b3r[16] = {Cq0.x,Cq0.y,Cq0.z,Cq0.w, Cq1.x,Cq1.y,Cq1.z,Cq1.w,
                         Cq2.x,Cq2.y,Cq2.z,Cq2.w, Cq3.x,Cq3.y,Cq3.z,Cq3.w};
  const float b2r[16] = {D0.x,D0.y,D0.z,D0.w, D1.x,D1.y,D1.z,D1.w,
                         D2.x,D2.y,D2.z,D2.w, D3.x,D3.y,D3.z,D3.w};
  const float b1r[8]  = {E0.x,E0.y,E0.z,E0.w, E1.x,E1.y,E1.z,E1.w};

#pragma unroll
  for (int l = 0; l < 8; ++l) {
    r4[l]     += b4r[l]     + a1i * b3r[l]     + a2v * b2r[l]     + r3[0] * b1r[l];
    r4[8 + l] += b4r[8 + l] + a1i * b3r[8 + l] + a2v * b2r[8 + l] + r3[1] * b1r[l];
  }
  r3[0] += b3c.x + a1i * b2jk.x + a2v * b1k.x;
  r3[1] += b3c.y + a1i * b2jk.y + a2v * b1k.y;
  const float a1i_old = a1i;
  a2v += b2ij + a1i_old * b1j;
  if (t < 64) { a2s += b2t + a1s * b1j2; a1s += b1i2; }
  a1i = a1i_old + b1i;
  if (t < 8) a1t += b1t;
}

// ---- fill per-chunk increment table (2 KB LDS) ----
__device__ __forceinline__ void fill_zbuf(float (*zbuf)[8], const float* __restrict__ path,
                                          int base, int t) {
  for (int u = t; u < CHUNK * 8; u += 256) {
    const int s = u >> 3, l = u & 7;
    const int rB = min(base + s + 1, NPATH - 1);
    zbuf[s][l] = path[rB * DIM + l] - path[(base + s) * DIM + l];
  }
}

// ---- exp-Chen step loop; STORE path does lane-contiguous stores via LDS transpose ----
template <bool STORE>
__device__ __forceinline__ void run_steps(const float (*zbuf)[8], float* lbuf,
                                          float* __restrict__ out, int base, int nsteps,
                                          float r4[16], float r3[2],
                                          float& a1i, float& a2v,
                                          float& a2s, float& a1s, float& a1t, int t) {
  const int i  = t >> 5;
  const int j  = (t >> 2) & 7;
  const int k0 = 2 * (t & 3);
  const int i2 = t >> 3;
  const int j2 = t & 7;
  const int tp = t >> 2;           // transpose: producer thread base
  const int rq = 4 * (t & 3);      // transpose: producer quad offset (floats)
  for (int s = 0; s < nsteps; ++s) {
    const float* zs = zbuf[s];
    const float zi = zs[i];
    const float zj = zs[j];
    const float2 zk = *(const float2*)(zs + k0);
    const float4 za = *(const float4*)zs;
    const float4 zb = *(const float4*)(zs + 4);
    const float zn[8] = {za.x, za.y, za.z, za.w, zb.x, zb.y, zb.z, zb.w};
    const float a1zi4 = a1i + 0.25f * zi;
    const float zj6   = C6 * zj;
    const float T0 = r3[0] + a2v * (0.5f * zk.x) + a1zi4 * (zj6 * zk.x);
    const float T1 = r3[1] + a2v * (0.5f * zk.y) + a1zi4 * (zj6 * zk.y);
    const float U  = a2v + (0.5f * a1i + C6 * zi) * zj;
#pragma unroll
    for (int l = 0; l < 8; ++l) {
      r4[l]     += T0 * zn[l];
      r4[8 + l] += T1 * zn[l];
    }
    r3[0] += zk.x * U;
    r3[1] += zk.y * U;
    a2v += (a1i + 0.5f * zi) * zj;
    a1i += zi;
    if (t < 64) {
      const float zi2 = zs[i2], zj2v = zs[j2];
      a2s += (a1s + 0.5f * zi2) * zj2v;
      a1s += zi2;
    }
    if (t < 8) a1t += zs[t];
    if constexpr (STORE) {
      // stage own 16 floats into padded LDS (17-float stride -> conflict-free)
      float* lb = lbuf + (s & 1) * (256 * LPAD) + LPAD * t;
      *(float4*)(lb + 0)  = make_float4(r4[0], r4[1], r4[2], r4[3]);
      *(float4*)(lb + 4)  = make_float4(r4[4], r4[5], r4[6], r4[7]);
      *(float4*)(lb + 8)  = make_float4(r4[8], r4[9], r4[10], r4[11]);
      *(float4*)(lb + 12) = make_float4(r4[12], r4[13], r4[14], r4[15]);
      light_barrier();
      const float* lbr = lbuf + (s & 1) * (256 * LPAD);
      float* dst = out + (size_t)(base + s) * SIG;
#pragma unroll
      for (int q = 0; q < 4; ++q) {
        // element e = 4t + 1024q : producer thread (t>>2)+64q, quad (t&3)
        const float4 v = *(const float4*)(lbr + LPAD * (tp + 64 * q) + rq);
        *(float4*)(dst + L4OFF + 4 * t + 1024 * q) = v;   // wave-contiguous 1 KB
      }
      *(float2*)(dst + L3OFF + 2 * t) = make_float2(r3[0], r3[1]);
      if (t < 64) dst[L2OFF + t] = a2s;
      if (t < 8)  dst[L1OFF + t] = a1t;
    }
  }
}

// ================= fused cooperative kernel =================
__global__ __launch_bounds__(256) void k_fused(const float* __restrict__ path,
                                               float* __restrict__ ws,
                                               float* __restrict__ out) {
  __shared__ float zbuf[CHUNK][8];
  __shared__ __align__(16) float ldsE[SIG];
  __shared__ __align__(16) float lbuf[2 * 256 * LPAD];
  const int t = threadIdx.x;
  const int b = blockIdx.x;
  const int g = b >> 4;            // group of GSIZE chunks
  const int base = b * CHUNK;
  const int n = min(CHUNK, NINC - base);
  float* totals = ws;                               // 256 * SIG
  float* GT     = ws + (size_t)NBLK * SIG;          // 16 * SIG

  // ---- Phase A: chunk total T_b ----
  fill_zbuf(zbuf, path, base, t);
  float r4[16], r3[2], a1i, a2v, a2s, a1s, a1t;
  zero_state(r4, r3, a1i, a2v, a2s, a1s, a1t);
  __syncthreads();
  run_steps<false>(zbuf, nullptr, nullptr, base, n, r4, r3, a1i, a2v, a2s, a1s, a1t, t);
  store_sig_reg(totals + (size_t)b * SIG, r4, r3, a2s, a1t, t);

  cg::this_grid().sync();

  // ---- Phase B: group-local exclusive prefix E_b = T_{16g} o ... o T_{b-1} ----
  zero_state(r4, r3, a1i, a2v, a2s, a1s, a1t);
  for (int m = g * GSIZE; m < b; ++m)
    chen_reg(r4, r3, a1i, a2v, a2s, a1s, a1t, totals + (size_t)m * SIG, t);
  if ((b & (GSIZE - 1)) == (GSIZE - 1)) {
    // last block of group: group total GT[g] = E_b o T_b
    float c4[16], c3[2];
#pragma unroll
    for (int l = 0; l < 16; ++l) c4[l] = r4[l];
    c3[0] = r3[0]; c3[1] = r3[1];
    float c1i = a1i, c2v = a2v, c2s = a2s, c1s = a1s, c1t = a1t;
    chen_reg(c4, c3, c1i, c2v, c2s, c1s, c1t, totals + (size_t)b * SIG, t);
    store_sig_reg(GT + (size_t)g * SIG, c4, c3, c2s, c1t, t);
  }
  store_sig_reg(ldsE, r4, r3, a2s, a1t, t);   // stage E_b for use as right-operand

  cg::this_grid().sync();

  // ---- Phase C: A_b = (GT_0 o ... o GT_{g-1}) o E_b ----
  zero_state(r4, r3, a1i, a2v, a2s, a1s, a1t);
  for (int gp = 0; gp < g; ++gp)
    chen_reg(r4, r3, a1i, a2v, a2s, a1s, a1t, GT + (size_t)gp * SIG, t);
  chen_reg(r4, r3, a1i, a2v, a2s, a1s, a1t, ldsE, t);

  // ---- Phase D: replay chunk, stream all rows (lane-contiguous stores) ----
  run_steps<true>(zbuf, lbuf, out, base, n, r4, r3, a1i, a2v, a2s, a1s, a1t, t);
}

extern "C" void kernel_launch(void* const* d_in, const int* in_sizes, int n_in,
                              void* d_out, int out_size, void* d_ws, size_t ws_size,
                              hipStream_t stream) {
  (void)in_sizes; (void)n_in; (void)out_size; (void)ws_size;
  const float* path = (const float*)d_in[0];
  float* out = (float*)d_out;
  float* ws = (float*)d_ws;
  void* args[] = {(void*)&path, (void*)&ws, (void*)&out};
  hipLaunchCooperativeKernel((const void*)k_fused, dim3(NBLK), dim3(256), args, 0, stream);
}

// Round 4
// 140.998 us; speedup vs baseline: 1.3723x; 1.3723x over previous
//
#include <hip/hip_runtime.h>

#define NPATH 16384
#define DIM   8
#define NINC  (NPATH - 1)        // 16383 output rows
#define SIG   4680               // 8 + 64 + 512 + 4096
#define L1OFF 0
#define L2OFF 8
#define L3OFF 72
#define L4OFF 584
#define NCHUNK 256               // 64-increment chunks
#define CHUNK  64
#define NSUB  2048               // 8-increment sub-chunks
#define SUB   8
#define NGRP  16
#define GSIZE 16
#define C6    0.16666666666666666f
#define LPAD  17                 // transpose buffer stride (16 + 1 pad floats)

// Per-thread register state (t in [0,256)):
//   r4[16]: level-4 rows 2t,2t+1 of [512][8]; r3[2]: level-3 elems 2t,2t+1
//   a1i=a1[t>>5], a2v=a2[t>>2] (consumed by L3/L4 updates)
//   a2s=a2[t] (t<64), a1s=a1[t>>3] (t<64), a1t=a1[t] (t<8) (store mapping)

__device__ __forceinline__ void light_barrier() {
  asm volatile("s_waitcnt lgkmcnt(0)" ::: "memory");
  __builtin_amdgcn_s_barrier();
}

__device__ __forceinline__ void zero_state(float r4[16], float r3[2],
                                           float& a1i, float& a2v,
                                           float& a2s, float& a1s, float& a1t) {
#pragma unroll
  for (int l = 0; l < 16; ++l) r4[l] = 0.f;
  r3[0] = r3[1] = 0.f;
  a1i = a2v = a2s = a1s = a1t = 0.f;
}

__device__ __forceinline__ void store_sig_reg(float* dst,
                                              const float r4[16], const float r3[2],
                                              float a2s, float a1t, int t) {
  float4* d4 = (float4*)(dst + L4OFF + 16 * t);
  d4[0] = make_float4(r4[0], r4[1], r4[2], r4[3]);
  d4[1] = make_float4(r4[4], r4[5], r4[6], r4[7]);
  d4[2] = make_float4(r4[8], r4[9], r4[10], r4[11]);
  d4[3] = make_float4(r4[12], r4[13], r4[14], r4[15]);
  *(float2*)(dst + L3OFF + 2 * t) = make_float2(r3[0], r3[1]);
  if (t < 64) dst[L2OFF + t] = a2s;
  if (t < 8)  dst[L1OFF + t] = a1t;
}

__device__ __forceinline__ void load_state(const float* __restrict__ src,
                                           float r4[16], float r3[2],
                                           float& a1i, float& a2v,
                                           float& a2s, float& a1s, float& a1t, int t) {
  const float4* s4 = (const float4*)(src + L4OFF + 16 * t);
  float4 G0 = s4[0], G1 = s4[1], G2 = s4[2], G3 = s4[3];
  r4[0]=G0.x; r4[1]=G0.y; r4[2]=G0.z; r4[3]=G0.w;
  r4[4]=G1.x; r4[5]=G1.y; r4[6]=G1.z; r4[7]=G1.w;
  r4[8]=G2.x; r4[9]=G2.y; r4[10]=G2.z; r4[11]=G2.w;
  r4[12]=G3.x; r4[13]=G3.y; r4[14]=G3.z; r4[15]=G3.w;
  const float2 gr3 = *(const float2*)(src + L3OFF + 2 * t);
  r3[0] = gr3.x; r3[1] = gr3.y;
  a1i = src[L1OFF + (t >> 5)];
  a2v = src[L2OFF + (t >> 2)];
  a2s = a1s = a1t = 0.f;
  if (t < 64) { a2s = src[L2OFF + t]; a1s = src[L1OFF + (t >> 3)]; }
  if (t < 8)  { a1t = src[L1OFF + t]; }
}

// ---- general Chen product a = a o b; b readable from global or LDS ----
__device__ __forceinline__ void chen_reg(float r4[16], float r3[2],
                                         float& a1i, float& a2v,
                                         float& a2s, float& a1s, float& a1t,
                                         const float* b, int t) {
  const int i   = t >> 5;
  const int j   = (t >> 2) & 7;
  const int ij  = t >> 2;
  const int c0  = 2 * t;
  const int jk0 = c0 & 63;
  const int k0  = 2 * (t & 3);
  const int i2  = t >> 3;
  const int j2  = t & 7;
  const float4* bv = (const float4*)b;
  float4 B0 = bv[146 + 4 * t], B1 = bv[147 + 4 * t], B2 = bv[148 + 4 * t], B3 = bv[149 + 4 * t];
  float4 Cq0 = bv[18 + 2 * jk0], Cq1 = bv[19 + 2 * jk0], Cq2 = bv[20 + 2 * jk0], Cq3 = bv[21 + 2 * jk0];
  float4 D0 = bv[2 + 2 * k0], D1 = bv[3 + 2 * k0], D2 = bv[4 + 2 * k0], D3 = bv[5 + 2 * k0];
  float4 E0 = bv[0], E1 = bv[1];
  const float2 b3c  = *(const float2*)(b + L3OFF + c0);
  const float2 b2jk = *(const float2*)(b + L2OFF + jk0);
  const float2 b1k  = *(const float2*)(b + L1OFF + k0);
  const float b2ij = b[L2OFF + ij];
  const float b1j  = b[L1OFF + j];
  const float b1i  = b[L1OFF + i];
  float b2t = 0.f, b1j2 = 0.f, b1i2 = 0.f, b1t = 0.f;
  if (t < 64) { b2t = b[L2OFF + t]; b1j2 = b[L1OFF + j2]; b1i2 = b[L1OFF + i2]; }
  if (t < 8)  { b1t = b[L1OFF + t]; }

  const float b4r[16] = {B0.x,B0.y,B0.z,B0.w, B1.x,B1.y,B1.z,B1.w,
                         B2.x,B2.y,B2.z,B2.w, B3.x,B3.y,B3.z,B3.w};
  const float b3r[16] = {Cq0.x,Cq0.y,Cq0.z,Cq0.w, Cq1.x,Cq1.y,Cq1.z,Cq1.w,
                         Cq2.x,Cq2.y,Cq2.z,Cq2.w, Cq3.x,Cq3.y,Cq3.z,Cq3.w};
  const float b2r[16] = {D0.x,D0.y,D0.z,D0.w, D1.x,D1.y,D1.z,D1.w,
                         D2.x,D2.y,D2.z,D2.w, D3.x,D3.y,D3.z,D3.w};
  const float b1r[8]  = {E0.x,E0.y,E0.z,E0.w, E1.x,E1.y,E1.z,E1.w};

#pragma unroll
  for (int l = 0; l < 8; ++l) {
    r4[l]     += b4r[l]     + a1i * b3r[l]     + a2v * b2r[l]     + r3[0] * b1r[l];
    r4[8 + l] += b4r[8 + l] + a1i * b3r[8 + l] + a2v * b2r[8 + l] + r3[1] * b1r[l];
  }
  r3[0] += b3c.x + a1i * b2jk.x + a2v * b1k.x;
  r3[1] += b3c.y + a1i * b2jk.y + a2v * b1k.y;
  const float a1i_old = a1i;
  a2v += b2ij + a1i_old * b1j;
  if (t < 64) { a2s += b2t + a1s * b1j2; a1s += b1i2; }
  a1i = a1i_old + b1i;
  if (t < 8) a1t += b1t;
}

// ---- one exp-Chen step (Horner form), register-only ----
__device__ __forceinline__ void step_update(const float* zs,
                                            float r4[16], float r3[2],
                                            float& a1i, float& a2v,
                                            float& a2s, float& a1s, float& a1t, int t) {
  const int i  = t >> 5;
  const int j  = (t >> 2) & 7;
  const int k0 = 2 * (t & 3);
  const int i2 = t >> 3;
  const int j2 = t & 7;
  const float zi = zs[i];
  const float zj = zs[j];
  const float2 zk = *(const float2*)(zs + k0);
  const float4 za = *(const float4*)zs;
  const float4 zb = *(const float4*)(zs + 4);
  const float zn[8] = {za.x, za.y, za.z, za.w, zb.x, zb.y, zb.z, zb.w};
  const float a1zi4 = a1i + 0.25f * zi;
  const float zj6   = C6 * zj;
  const float T0 = r3[0] + a2v * (0.5f * zk.x) + a1zi4 * (zj6 * zk.x);
  const float T1 = r3[1] + a2v * (0.5f * zk.y) + a1zi4 * (zj6 * zk.y);
  const float U  = a2v + (0.5f * a1i + C6 * zi) * zj;
#pragma unroll
  for (int l = 0; l < 8; ++l) {
    r4[l]     += T0 * zn[l];
    r4[8 + l] += T1 * zn[l];
  }
  r3[0] += zk.x * U;
  r3[1] += zk.y * U;
  a2v += (a1i + 0.5f * zi) * zj;
  a1i += zi;
  if (t < 64) {
    const float zi2 = zs[i2], zj2v = zs[j2];
    a2s += (a1s + 0.5f * zi2) * zj2v;
    a1s += zi2;
  }
  if (t < 8) a1t += zs[t];
}

// ================= K1: chunk totals + intra-chunk snapshots =================
__global__ __launch_bounds__(256) void k_totals(const float* __restrict__ path,
                                                float* __restrict__ T64,
                                                float* __restrict__ snap) {
  __shared__ float zbuf[CHUNK][8];
  const int t = threadIdx.x;
  const int b = blockIdx.x;
  const int base = b * CHUNK;
  for (int u = t; u < CHUNK * 8; u += 256) {
    const int s = u >> 3, l = u & 7;
    const int rB = min(base + s + 1, NPATH - 1);
    zbuf[s][l] = path[rB * DIM + l] - path[(base + s) * DIM + l];   // z=0 pad at end
  }
  float r4[16], r3[2], a1i, a2v, a2s, a1s, a1t;
  zero_state(r4, r3, a1i, a2v, a2s, a1s, a1t);
  __syncthreads();
  for (int w = 0; w < 8; ++w) {
    store_sig_reg(snap + ((size_t)b * 8 + w) * SIG, r4, r3, a2s, a1t, t);
#pragma unroll
    for (int s2 = 0; s2 < 8; ++s2)
      step_update(zbuf[8 * w + s2], r4, r3, a1i, a2v, a2s, a1s, a1t, t);
  }
  store_sig_reg(T64 + (size_t)b * SIG, r4, r3, a2s, a1t, t);
}

// ================= K2/K3: sequential scan of `count` signatures per block =================
__global__ __launch_bounds__(256) void k_scan(const float* __restrict__ in,
                                              float* __restrict__ prefout,
                                              float* __restrict__ totout,
                                              int count) {
  const int t = threadIdx.x;
  const size_t goff = (size_t)blockIdx.x * count;
  float r4[16], r3[2], a1i, a2v, a2s, a1s, a1t;
  zero_state(r4, r3, a1i, a2v, a2s, a1s, a1t);
  for (int m = 0; m < count; ++m) {
    store_sig_reg(prefout + (goff + m) * SIG, r4, r3, a2s, a1t, t);   // exclusive prefix
    chen_reg(r4, r3, a1i, a2v, a2s, a1s, a1t, in + (goff + m) * SIG, t);
  }
  if (totout != nullptr) store_sig_reg(totout + (size_t)blockIdx.x * SIG, r4, r3, a2s, a1t, t);
}

// ================= K4: 2048 blocks x 8 rows, stream output =================
__global__ __launch_bounds__(256) void k_out(const float* __restrict__ path,
                                             const float* __restrict__ pref,
                                             const float* __restrict__ gpref,
                                             const float* __restrict__ snap,
                                             float* __restrict__ out) {
  __shared__ float zbuf[SUB][8];
  __shared__ __align__(16) float lbuf[256 * LPAD];
  const int t = threadIdx.x;
  const int sIdx = blockIdx.x;
  const int b = sIdx >> 3;         // chunk64
  const int g = b >> 4;            // group
  const int base = sIdx * SUB;
  const int n = min(SUB, NINC - base);
  if (t < SUB * 8) {
    const int s = t >> 3, l = t & 7;
    const int rB = min(base + s + 1, NPATH - 1);
    zbuf[s][l] = path[rB * DIM + l] - path[(base + s) * DIM + l];
  }
  float r4[16], r3[2], a1i, a2v, a2s, a1s, a1t;
  load_state(gpref + (size_t)g * SIG, r4, r3, a1i, a2v, a2s, a1s, a1t, t);
  chen_reg(r4, r3, a1i, a2v, a2s, a1s, a1t, pref + (size_t)b * SIG, t);
  chen_reg(r4, r3, a1i, a2v, a2s, a1s, a1t, snap + (size_t)sIdx * SIG, t);
  __syncthreads();   // zbuf ready
  const int tp = t >> 2;
  const int rq = 4 * (t & 3);
  for (int s2 = 0; s2 < n; ++s2) {
    step_update(zbuf[s2], r4, r3, a1i, a2v, a2s, a1s, a1t, t);
    // stage own 16 floats into padded LDS, then lane-contiguous global stores
    float* lb = lbuf + LPAD * t;
    *(float4*)(lb + 0)  = make_float4(r4[0], r4[1], r4[2], r4[3]);
    *(float4*)(lb + 4)  = make_float4(r4[4], r4[5], r4[6], r4[7]);
    *(float4*)(lb + 8)  = make_float4(r4[8], r4[9], r4[10], r4[11]);
    *(float4*)(lb + 12) = make_float4(r4[12], r4[13], r4[14], r4[15]);
    light_barrier();
    float* dst = out + (size_t)(base + s2) * SIG;
#pragma unroll
    for (int q = 0; q < 4; ++q) {
      const float4 v = *(const float4*)(lbuf + LPAD * (tp + 64 * q) + rq);
      *(float4*)(dst + L4OFF + 4 * t + 1024 * q) = v;
    }
    *(float2*)(dst + L3OFF + 2 * t) = make_float2(r3[0], r3[1]);
    if (t < 64) dst[L2OFF + t] = a2s;
    if (t < 8)  dst[L1OFF + t] = a1t;
    light_barrier();   // reads done before next iter's LDS writes
  }
}

extern "C" void kernel_launch(void* const* d_in, const int* in_sizes, int n_in,
                              void* d_out, int out_size, void* d_ws, size_t ws_size,
                              hipStream_t stream) {
  (void)in_sizes; (void)n_in; (void)out_size; (void)ws_size;
  const float* path = (const float*)d_in[0];
  float* out = (float*)d_out;
  float* ws = (float*)d_ws;

  float* T64   = ws;                                 // 256 * SIG
  float* pref  = T64   + (size_t)NCHUNK * SIG;       // 256 * SIG
  float* gtot  = pref  + (size_t)NCHUNK * SIG;       // 16 * SIG
  float* gpref = gtot  + (size_t)NGRP * SIG;         // 16 * SIG
  float* snap  = gpref + (size_t)NGRP * SIG;         // 2048 * SIG

  k_totals<<<NCHUNK, 256, 0, stream>>>(path, T64, snap);
  k_scan<<<NGRP, 256, 0, stream>>>(T64, pref, gtot, GSIZE);
  k_scan<<<1, 256, 0, stream>>>(gtot, gpref, nullptr, NGRP);
  k_out<<<NSUB, 256, 0, stream>>>(path, pref, gpref, snap, out);
}